// Round 8
// baseline (313.034 us; speedup 1.0000x reference)
//
#include <hip/hip_runtime.h>
#include <math.h>

#define D 128
#define NPB 8
#define EPS1 (1.0f + 1e-6f)

// ---- DPP row_ror sum over each 16-lane row: all lanes get the total ----
__device__ __forceinline__ float dpp_rsum16(float v) {
    v += __int_as_float(__builtin_amdgcn_update_dpp(
        0, __float_as_int(v), 0x121, 0xf, 0xf, true));  // ror:1
    v += __int_as_float(__builtin_amdgcn_update_dpp(
        0, __float_as_int(v), 0x122, 0xf, 0xf, true));  // ror:2
    v += __int_as_float(__builtin_amdgcn_update_dpp(
        0, __float_as_int(v), 0x124, 0xf, 0xf, true));  // ror:4
    v += __int_as_float(__builtin_amdgcn_update_dpp(
        0, __float_as_int(v), 0x128, 0xf, 0xf, true));  // ror:8
    return v;
}

// fast acosh for a >= 1+1e-6
__device__ __forceinline__ float facosh(float a) {
    return __logf(a + sqrtf(fmaxf(a * a - 1.0f, 0.0f)));
}

__device__ __forceinline__ void unpack8(const float4& a, const float4& b,
                                        float* d) {
    d[0] = a.x; d[1] = a.y; d[2] = a.z; d[3] = a.w;
    d[4] = b.x; d[5] = b.y; d[6] = b.z; d[7] = b.w;
}

// ---------------------------------------------------------------------------
// Kernel 1: per-node pre-processing. 512 threads = (j in [0,128)) x (kp in
// {0..3}). Elementwise phases: quarter kp owns nodes [kp*2, kp*2+2).
// Matmuls: thread (j,kp) computes partials over k in [kp*32,(kp+1)*32) for
// ALL 8 nodes; partials merge through LDS psum. 1250 blocks x 8 waves.
// ---------------------------------------------------------------------------
__device__ __forceinline__ void bsumH2(float* v, float (*wred)[2], int lane,
                                       int wid, int kp) {
    __syncthreads();  // protect wred reuse
#pragma unroll
    for (int o = 32; o; o >>= 1)
#pragma unroll
        for (int nl = 0; nl < 2; nl++) v[nl] += __shfl_xor(v[nl], o, 64);
    if (lane == 0)
#pragma unroll
        for (int nl = 0; nl < 2; nl++) wred[wid][nl] = v[nl];
    __syncthreads();
#pragma unroll
    for (int nl = 0; nl < 2; nl++)
        v[nl] = wred[2 * kp][nl] + wred[2 * kp + 1][nl];
}

__global__ __launch_bounds__(512) void node_pre8(
    const float* __restrict__ h, const float* __restrict__ W,
    const float* __restrict__ bias, const float* __restrict__ att_w1,
    const float* __restrict__ att_b1, float* __restrict__ XQ,
    float* __restrict__ P_out, const int* __restrict__ row,
    int* __restrict__ cnt, int N, int E) {
    int i0 = blockIdx.x * NPB;
    int tid = threadIdx.x;
    int j = tid & 127, kp = tid >> 7;
    int lane = tid & 63, wid = tid >> 6;
    int nbase = kp * 2;
    __shared__ __align__(16) float t8[NPB][D];
    __shared__ float psumP[4][NPB][D];
    __shared__ float psumQ[4][NPB][D];
    __shared__ float wred[8][2];

    // logmap0(h) — own 2 nodes
    float hj[2];
#pragma unroll
    for (int nl = 0; nl < 2; nl++) {
        int gi = i0 + nbase + nl;
        hj[nl] = (gi < N) ? h[(size_t)gi * D + j] : 0.0f;
        t8[nbase + nl][j] = hj[nl];
    }
    __syncthreads();
    float tj[2];
#pragma unroll
    for (int nl = 0; nl < 2; nl++) {
        float h0 = fmaxf(t8[nbase + nl][0], EPS1);
        float fac = facosh(h0) * rsqrtf(h0 * h0 - 1.0f);
        tj[nl] = (j == 0) ? 0.0f : hj[nl] * fac;
    }
    __syncthreads();
#pragma unroll
    for (int nl = 0; nl < 2; nl++) t8[nbase + nl][j] = tj[nl];
    __syncthreads();

    // xt partial over this thread's k-quarter, all 8 nodes
    float xtp[NPB];
#pragma unroll
    for (int n = 0; n < NPB; n++) xtp[n] = 0.0f;
    int kbeg = kp * 32;
    for (int k0 = kbeg; k0 < kbeg + 32; k0 += 4) {
        float w0 = W[(k0 + 0) * D + j], w1 = W[(k0 + 1) * D + j];
        float w2 = W[(k0 + 2) * D + j], w3 = W[(k0 + 3) * D + j];
#pragma unroll
        for (int n = 0; n < NPB; n++) {
            float4 tv = *(const float4*)&t8[n][k0];
            xtp[n] = fmaf(tv.x, w0,
                          fmaf(tv.y, w1, fmaf(tv.z, w2, fmaf(tv.w, w3, xtp[n]))));
        }
    }
#pragma unroll
    for (int n = 0; n < NPB; n++) psumP[kp][n][j] = xtp[n];
    __syncthreads();
    float xt[2];
#pragma unroll
    for (int nl = 0; nl < 2; nl++) {
        int n = nbase + nl;
        xt[nl] = (j == 0) ? 0.0f
                          : (psumP[0][n][j] + psumP[1][n][j] + psumP[2][n][j] +
                             psumP[3][n][j]);
    }

    // x = expmap0([0, xt])
    float v2[2];
#pragma unroll
    for (int nl = 0; nl < 2; nl++) v2[nl] = xt[nl] * xt[nl];
    bsumH2(v2, wred, lane, wid, kp);
    float xj[2];
#pragma unroll
    for (int nl = 0; nl < 2; nl++) {
        float nn = sqrtf(fmaxf(v2[nl], 1e-6f));
        float e = __expf(nn), ei = __fdividef(1.0f, e);
        float ch = 0.5f * (e + ei), sh = 0.5f * (e - ei);
        xj[nl] = (j == 0) ? ch : __fdividef(sh, nn) * xt[nl];
    }

    // b = transp0(x, [0,bias]); x = expmap(x, b)
    float vj = (j == 0) ? 0.0f : bias[j];
#pragma unroll
    for (int nl = 0; nl < 2; nl++) v2[nl] = xj[nl] * vj;
    bsumH2(v2, wred, lane, wid, kp);
    __syncthreads();
#pragma unroll
    for (int nl = 0; nl < 2; nl++) t8[nbase + nl][j] = xj[nl];
    __syncthreads();
    float bj[2];
#pragma unroll
    for (int nl = 0; nl < 2; nl++) {
        float X0 = t8[nbase + nl][0];
        float coef = __fdividef(v2[nl], 1.0f + X0);
        bj[nl] = vj + coef * ((j == 0) ? (X0 + 1.0f) : xj[nl]);
    }
#pragma unroll
    for (int nl = 0; nl < 2; nl++)
        v2[nl] = (j == 0) ? -bj[nl] * bj[nl] : bj[nl] * bj[nl];
    bsumH2(v2, wred, lane, wid, kp);
    float xnj[2];
#pragma unroll
    for (int nl = 0; nl < 2; nl++) {
        float nb = sqrtf(fmaxf(v2[nl], 1e-6f));
        float e = __expf(nb), ei = __fdividef(1.0f, e);
        float ch = 0.5f * (e + ei), sh = 0.5f * (e - ei);
        xnj[nl] = ch * xj[nl] + __fdividef(sh, nb) * bj[nl];
        int gi = i0 + nbase + nl;
        if (gi < N) XQ[(size_t)gi * 256 + j] = xnj[nl];
    }

    // x_tan = logmap0(x) -> t8
    __syncthreads();
#pragma unroll
    for (int nl = 0; nl < 2; nl++) t8[nbase + nl][j] = xnj[nl];
    __syncthreads();
    float xtj[2];
#pragma unroll
    for (int nl = 0; nl < 2; nl++) {
        float Y0 = fmaxf(t8[nbase + nl][0], EPS1);
        float f = facosh(Y0) * rsqrtf(Y0 * Y0 - 1.0f);
        xtj[nl] = (j == 0) ? 0.0f : xnj[nl] * f;
    }
    __syncthreads();
#pragma unroll
    for (int nl = 0; nl < 2; nl++) t8[nbase + nl][j] = xtj[nl];
    __syncthreads();

    // P/Q partials over k-quarter, all 8 nodes
    float pp[NPB], qq[NPB];
#pragma unroll
    for (int n = 0; n < NPB; n++) {
        pp[n] = 0.0f;
        qq[n] = 0.0f;
    }
    for (int k0 = kbeg; k0 < kbeg + 32; k0 += 4) {
        float a0 = att_w1[(k0 + 0) * D + j], a1 = att_w1[(k0 + 1) * D + j];
        float a2 = att_w1[(k0 + 2) * D + j], a3 = att_w1[(k0 + 3) * D + j];
        float c0 = att_w1[(D + k0 + 0) * D + j], c1 = att_w1[(D + k0 + 1) * D + j];
        float c2 = att_w1[(D + k0 + 2) * D + j], c3 = att_w1[(D + k0 + 3) * D + j];
#pragma unroll
        for (int n = 0; n < NPB; n++) {
            float4 tv = *(const float4*)&t8[n][k0];
            pp[n] = fmaf(tv.x, a0,
                         fmaf(tv.y, a1, fmaf(tv.z, a2, fmaf(tv.w, a3, pp[n]))));
            qq[n] = fmaf(tv.x, c0,
                         fmaf(tv.y, c1, fmaf(tv.z, c2, fmaf(tv.w, c3, qq[n]))));
        }
    }
#pragma unroll
    for (int n = 0; n < NPB; n++) {
        psumP[kp][n][j] = pp[n];
        psumQ[kp][n][j] = qq[n];
    }
    __syncthreads();
    float b1 = att_b1[j];
#pragma unroll
    for (int nl = 0; nl < 2; nl++) {
        int n = nbase + nl;
        int gi = i0 + n;
        if (gi < N) {
            P_out[(size_t)gi * D + j] = psumP[0][n][j] + psumP[1][n][j] +
                                        psumP[2][n][j] + psumP[3][n][j] + b1;
            XQ[(size_t)gi * 256 + 128 + j] = psumQ[0][n][j] + psumQ[1][n][j] +
                                             psumQ[2][n][j] + psumQ[3][n][j];
        }
    }

    // ---- folded histogram ----
    int gtid = blockIdx.x * 512 + tid;
    int tot = gridDim.x * 512;
    for (int e2 = gtid; e2 < E; e2 += tot) atomicAdd(&cnt[row[e2]], 1);
}

// ---------------------------------------------------------------------------
// CSR build: scan + scatter
// ---------------------------------------------------------------------------
__global__ __launch_bounds__(1024) void scan_kernel(const int* __restrict__ cnt,
                                                    int* __restrict__ off,
                                                    int* __restrict__ cursor,
                                                    int N) {
    __shared__ int wsum[16];
    __shared__ int carry_s;
    int tid = threadIdx.x, lane = tid & 63, wid = tid >> 6;
    if (tid == 0) carry_s = 0;
    __syncthreads();
    for (int base = 0; base < N; base += 1024) {
        int idx = base + tid;
        int v = (idx < N) ? cnt[idx] : 0;
        int orig = v;
#pragma unroll
        for (int o = 1; o < 64; o <<= 1) {
            int t = __shfl_up(v, o, 64);
            if (lane >= o) v += t;
        }
        if (lane == 63) wsum[wid] = v;
        __syncthreads();
        if (wid == 0 && lane < 16) {
            int w = wsum[lane];
#pragma unroll
            for (int o = 1; o < 16; o <<= 1) {
                int t = __shfl_up(w, o, 64);
                if (lane >= o) w += t;
            }
            wsum[lane] = w;
        }
        __syncthreads();
        int carry = carry_s;
        int wbase = (wid == 0) ? 0 : wsum[wid - 1];
        int excl = carry + wbase + v - orig;
        if (idx < N) {
            off[idx] = excl;
            cursor[idx] = excl;
        }
        __syncthreads();
        if (tid == 1023) carry_s = carry + wsum[15];
        __syncthreads();
    }
}

__global__ void scatter_kernel(const int* __restrict__ row,
                               const int* __restrict__ col,
                               const float* __restrict__ edge_attr,
                               const float* __restrict__ edge_mask,
                               int* __restrict__ cursor,
                               float4* __restrict__ rec, int E) {
    const float2* ea2 = (const float2*)edge_attr;
    for (int e = blockIdx.x * blockDim.x + threadIdx.x; e < E;
         e += gridDim.x * blockDim.x) {
        int r = row[e];
        int pos = atomicAdd(&cursor[r], 1);
        float2 a = ea2[e];
        rec[pos] = make_float4(__int_as_float(col[e]), a.x, a.y, edge_mask[e]);
    }
}

// ---------------------------------------------------------------------------
// Kernel D: PERSISTENT edge aggregation + fused epilogue. 2048 blocks = 8192
// waves stay resident; each wave pops nodes off a global work counter
// (work-stealing balances degree variance and removes the grid tail).
// Per node: 4 chunks, one per 16-lane group; DPP reductions; register-only
// epilogue; group 0 stores. No LDS, no barriers.
// ---------------------------------------------------------------------------
__global__ __launch_bounds__(256) void edge_agg(
    const float* __restrict__ XQ, const float* __restrict__ P,
    const float4* __restrict__ rec, const int* __restrict__ off,
    const int* __restrict__ cnt, const float* __restrict__ w1c,
    const float* __restrict__ att_w2, const float* __restrict__ att_b2,
    const float* __restrict__ gamma, const float* __restrict__ beta,
    float* __restrict__ out, int* __restrict__ wctr, int N) {
    int tid = threadIdx.x, lane = tid & 63;
    int sub = lane & 15, grp = lane >> 4;
    int j8 = sub * 8, f4 = sub * 2;

    // node-independent state (hoisted out of the work loop)
    const float4* w4 = (const float4*)w1c;
    const float4* aw4 = (const float4*)att_w2;
    float wa[8], wb[8], wg[8], w2v[8];
    unpack8(w4[f4], w4[f4 + 1], wa);
    unpack8(w4[32 + f4], w4[32 + f4 + 1], wb);
    unpack8(w4[64 + f4], w4[64 + f4 + 1], wg);
    unpack8(aw4[f4], aw4[f4 + 1], w2v);
    float b2 = att_b2[0];
    float g_ln[8], bt_ln[8];
#pragma unroll
    for (int u = 0; u < 8; u++) {
        int j = j8 + u;
        g_ln[u] = (j > 0) ? gamma[j - 1] : 0.0f;
        bt_ln[u] = (j > 0) ? beta[j - 1] : 0.0f;
    }

    for (;;) {
        int ipop;
        if (lane == 0) ipop = atomicAdd(wctr, 1);
        int i = __builtin_amdgcn_readfirstlane(ipop);
        if (i >= N) break;

        const float4* xq4r = (const float4*)(XQ + (size_t)i * 256);
        const float4* pr4 = (const float4*)(P + (size_t)i * D);
        float xr[8], pr[8];
        unpack8(xq4r[f4], xq4r[f4 + 1], xr);
        unpack8(pr4[f4], pr4[f4 + 1], pr);
        float xr0s = (sub == 0) ? -xr[0] : xr[0];

        float acc[8];
#pragma unroll
        for (int u = 0; u < 8; u++) acc[u] = 0.0f;

        int s = off[i], m = cnt[i];
        int clen = (m + 3) >> 2;           // wave-uniform chunk length
        int k0 = grp * clen;
        int len = min(m, k0 + clen) - k0;  // may be <=0 for trailing groups

        auto compute = [&](const float4& rc, const float4& g0, const float4& g1,
                           const float4& g2, const float4& g3, bool act) {
            float xc[8], qc[8];
            unpack8(g0, g1, xc);
            unpack8(g2, g3, qc);
            float lin = xr0s * xc[0];
#pragma unroll
            for (int u = 1; u < 8; u++) lin = fmaf(xr[u], xc[u], lin);
            lin = dpp_rsum16(lin);
            float alpha = fmaxf(-lin, EPS1);
            float a2m = fmaxf(fmaf(alpha, alpha, -1.0f), 1e-12f);
            float rden = rsqrtf(a2m);
            float geo = __logf(fmaf(a2m, rden, alpha));  // acosh(alpha)
            float lp = 0.0f;
#pragma unroll
            for (int u = 0; u < 8; u++) {
                float hv = pr[u] + qc[u] +
                           fmaf(rc.y, wa[u], fmaf(rc.z, wb[u], geo * wg[u]));
                float sig = __fdividef(1.0f, 1.0f + __expf(-hv));
                lp = fmaf(hv * sig, w2v[u], lp);  // silu(h)*w2
            }
            lp = dpp_rsum16(lp);
            float w = act ? rc.w : 0.0f;
            float att = w * __fdividef(1.0f, 1.0f + __expf(-(lp + b2)));
            float scale = att * geo * rden * 1e-3f;
#pragma unroll
            for (int u = 0; u < 8; u++)
                acc[u] = fmaf(scale, fmaf(-alpha, xr[u], xc[u]), acc[u]);
        };

        // software-pipelined chunk loop (depth 2), wave-uniform bound
        float4 rcA = make_float4(__int_as_float(0), 0.0f, 0.0f, 0.0f), rcB;
        if (len > 0) rcA = rec[s + k0];
        const float4* pA =
            (const float4*)(XQ + (size_t)__float_as_int(rcA.x) * 256);
        float4 gA0 = pA[f4], gA1 = pA[f4 + 1], gA2 = pA[32 + f4],
               gA3 = pA[32 + f4 + 1];
        float4 gB0, gB1, gB2, gB3;

        for (int t = 0; t < clen; t += 2) {
            rcB = rcA;
            if (t + 1 < len) rcB = rec[s + k0 + t + 1];
            const float4* pB =
                (const float4*)(XQ + (size_t)__float_as_int(rcB.x) * 256);
            gB0 = pB[f4]; gB1 = pB[f4 + 1]; gB2 = pB[32 + f4];
            gB3 = pB[32 + f4 + 1];
            compute(rcA, gA0, gA1, gA2, gA3, t < len);
            rcA = rcB;
            if (t + 2 < len) rcA = rec[s + k0 + t + 2];
            const float4* pN =
                (const float4*)(XQ + (size_t)__float_as_int(rcA.x) * 256);
            gA0 = pN[f4]; gA1 = pN[f4 + 1]; gA2 = pN[32 + f4];
            gA3 = pN[32 + f4 + 1];
            compute(rcB, gB0, gB1, gB2, gB3, t + 1 < len);
        }

        // merge the 4 chunk-partials: every lane gets the full sum
#pragma unroll
        for (int u = 0; u < 8; u++) {
            acc[u] += __shfl_xor(acc[u], 16, 64);
            acc[u] += __shfl_xor(acc[u], 32, 64);
        }

        // fused epilogue (all lanes compute; grp 0 stores)
        float lxa_p = (sub == 0) ? -xr[0] * acc[0] : xr[0] * acc[0];
#pragma unroll
        for (int u = 1; u < 8; u++) lxa_p = fmaf(xr[u], acc[u], lxa_p);
        float lxa = dpp_rsum16(lxa_p);
        float uj[8];
#pragma unroll
        for (int u = 0; u < 8; u++) uj[u] = fmaf(lxa, xr[u], acc[u]);
        float luu_p = (sub == 0) ? -uj[0] * uj[0] : uj[0] * uj[0];
#pragma unroll
        for (int u = 1; u < 8; u++) luu_p = fmaf(uj[u], uj[u], luu_p);
        float luu = dpp_rsum16(luu_p);
        float nn = sqrtf(fmaxf(luu, 1e-6f));
        float e = __expf(nn), ei = __fdividef(1.0f, e);
        float ch = 0.5f * (e + ei), shv = __fdividef(0.5f * (e - ei), nn);
        float xn[8];
#pragma unroll
        for (int u = 0; u < 8; u++) xn[u] = ch * xr[u] + shv * uj[u];
        float X0 = __shfl(xn[0], lane & 48, 64);  // group-base lane's j=0
        X0 = fmaxf(X0, EPS1);
        float fc = facosh(X0) * rsqrtf(X0 * X0 - 1.0f);
        float ht[8];
#pragma unroll
        for (int u = 0; u < 8; u++) ht[u] = xn[u] * fc;
        if (sub == 0) ht[0] = 0.0f;
        float mp = 0.0f;
#pragma unroll
        for (int u = 0; u < 8; u++) mp += ht[u];
        float mean = dpp_rsum16(mp) * (1.0f / 127.0f);
        float diff[8];
#pragma unroll
        for (int u = 0; u < 8; u++) diff[u] = ht[u] - mean;
        if (sub == 0) diff[0] = 0.0f;
        float vp = 0.0f;
#pragma unroll
        for (int u = 0; u < 8; u++) vp = fmaf(diff[u], diff[u], vp);
        float var = dpp_rsum16(vp) * (1.0f / 127.0f);
        float rstd = rsqrtf(var + 1e-5f);
        float sp[8];
#pragma unroll
        for (int u = 0; u < 8; u++)
            sp[u] = fmaf(diff[u] * rstd, g_ln[u], bt_ln[u]);
        if (sub == 0) sp[0] = 0.0f;
        float n2p = 0.0f;
#pragma unroll
        for (int u = 0; u < 8; u++) n2p = fmaf(sp[u], sp[u], n2p);
        float n2 = sqrtf(fmaxf(dpp_rsum16(n2p), 1e-6f));
        e = __expf(n2);
        ei = __fdividef(1.0f, e);
        float y0 = 0.5f * (e + ei), sh2 = __fdividef(0.5f * (e - ei), n2);
        float yj[8];
#pragma unroll
        for (int u = 0; u < 8; u++) yj[u] = sh2 * sp[u];
        if (sub == 0) yj[0] = y0;
        float y0c = fmaxf(y0, EPS1);
        float f3 = facosh(y0c) * rsqrtf(y0c * y0c - 1.0f);
        float sj[8];
#pragma unroll
        for (int u = 0; u < 8; u++) {
            float lj = yj[u] * f3;
            sj[u] = __fdividef(lj, 1.0f + __expf(-lj));
        }
        if (sub == 0) sj[0] = 0.0f;
        float n3p = 0.0f;
#pragma unroll
        for (int u = 0; u < 8; u++) n3p = fmaf(sj[u], sj[u], n3p);
        float n3 = sqrtf(fmaxf(dpp_rsum16(n3p), 1e-6f));
        e = __expf(n3);
        ei = __fdividef(1.0f, e);
        float o0 = 0.5f * (e + ei), sh3 = __fdividef(0.5f * (e - ei), n3);
        float ov[8];
#pragma unroll
        for (int u = 0; u < 8; u++) ov[u] = sh3 * sj[u];
        if (sub == 0) ov[0] = o0;
        if (grp == 0) {
            float4* o4 = (float4*)(out + (size_t)i * D);
            o4[f4] = make_float4(ov[0], ov[1], ov[2], ov[3]);
            o4[f4 + 1] = make_float4(ov[4], ov[5], ov[6], ov[7]);
        }
    }
}

extern "C" void kernel_launch(void* const* d_in, const int* in_sizes, int n_in,
                              void* d_out, int out_size, void* d_ws,
                              size_t ws_size, hipStream_t stream) {
    const float* h = (const float*)d_in[0];
    const float* edge_attr = (const float*)d_in[1];
    const int* row = (const int*)d_in[2];
    const int* col = (const int*)d_in[3];
    const float* edge_mask = (const float*)d_in[5];
    const float* W = (const float*)d_in[6];
    const float* bias = (const float*)d_in[7];
    const float* att_w1 = (const float*)d_in[8];
    const float* att_b1 = (const float*)d_in[9];
    const float* att_w2 = (const float*)d_in[10];
    const float* att_b2 = (const float*)d_in[11];
    const float* ln_g = (const float*)d_in[12];
    const float* ln_b = (const float*)d_in[13];

    int N = in_sizes[0] / D;
    int E = in_sizes[2];

    float* XQ = (float*)d_ws;                       // N*256
    float* Pbuf = XQ + (size_t)N * 256;             // N*128
    float4* rec = (float4*)(Pbuf + (size_t)N * D);  // E
    int* cnt = (int*)(rec + E);
    int* off = cnt + N;
    int* cur = off + N;
    int* wctr = cur + N;

    hipMemsetAsync(cnt, 0, N * sizeof(int), stream);
    hipMemsetAsync(wctr, 0, sizeof(int), stream);
    node_pre8<<<(N + NPB - 1) / NPB, 512, 0, stream>>>(
        h, W, bias, att_w1, att_b1, XQ, Pbuf, row, cnt, N, E);
    scan_kernel<<<1, 1024, 0, stream>>>(cnt, off, cur, N);
    scatter_kernel<<<640, 256, 0, stream>>>(row, col, edge_attr, edge_mask,
                                            cur, rec, E);
    edge_agg<<<2048, 256, 0, stream>>>(XQ, Pbuf, rec, off, cnt,
                                       att_w1 + 256 * D, att_w2, att_b2, ln_g,
                                       ln_b, (float*)d_out, wctr, N);
}

// Round 9
// 154.236 us; speedup vs baseline: 2.0296x; 2.0296x over previous
//
#include <hip/hip_runtime.h>
#include <math.h>

#define D 128
#define EPS1 (1.0f + 1e-6f)

// ---- DPP row_ror sum over each 16-lane row: all lanes get the total ----
__device__ __forceinline__ float dpp_rsum16(float v) {
    v += __int_as_float(__builtin_amdgcn_update_dpp(
        0, __float_as_int(v), 0x121, 0xf, 0xf, true));  // ror:1
    v += __int_as_float(__builtin_amdgcn_update_dpp(
        0, __float_as_int(v), 0x122, 0xf, 0xf, true));  // ror:2
    v += __int_as_float(__builtin_amdgcn_update_dpp(
        0, __float_as_int(v), 0x124, 0xf, 0xf, true));  // ror:4
    v += __int_as_float(__builtin_amdgcn_update_dpp(
        0, __float_as_int(v), 0x128, 0xf, 0xf, true));  // ror:8
    return v;
}

// full 64-lane sum, all lanes get the total
__device__ __forceinline__ float wsum64(float v) {
    v = dpp_rsum16(v);
    v += __shfl_xor(v, 16, 64);
    v += __shfl_xor(v, 32, 64);
    return v;
}

// fast acosh for a >= 1+1e-6
__device__ __forceinline__ float facosh(float a) {
    return __logf(a + sqrtf(fmaxf(a * a - 1.0f, 0.0f)));
}

__device__ __forceinline__ void unpack8(const float4& a, const float4& b,
                                        float* d) {
    d[0] = a.x; d[1] = a.y; d[2] = a.z; d[3] = a.w;
    d[4] = b.x; d[5] = b.y; d[6] = b.z; d[7] = b.w;
}

// ---------------------------------------------------------------------------
// Kernel 1: per-node pre-processing, BARRIER-FREE. One wave owns 4 nodes;
// lane covers j in {2*lane, 2*lane+1} for every phase. Cross-j exchange via
// per-wave LDS rows (DS ops are wave-ordered -> no __syncthreads at all).
// Block 256 = 4 independent waves = 16 nodes. Tail: grid-stride histogram.
// ---------------------------------------------------------------------------
__global__ __launch_bounds__(256) void node_pre16(
    const float* __restrict__ h, const float* __restrict__ W,
    const float* __restrict__ bias, const float* __restrict__ att_w1,
    const float* __restrict__ att_b1, float* __restrict__ XQ,
    float* __restrict__ P_out, const int* __restrict__ row,
    int* __restrict__ cnt, int N, int E) {
    int tid = threadIdx.x, lane = tid & 63, wv = tid >> 6;
    int base = blockIdx.x * 16 + wv * 4;
    int j0 = 2 * lane;
    __shared__ __align__(16) float ts[16][D];  // 8 KB; wave wv owns rows 4wv..

    int gi[4];
    bool val[4];
#pragma unroll
    for (int n = 0; n < 4; n++) {
        val[n] = base + n < N;
        gi[n] = min(base + n, N - 1);
    }

    // ---- logmap0(h) -> t -> LDS ----
    float ta[4], tb[4];
#pragma unroll
    for (int n = 0; n < 4; n++) {
        float2 h2 = *(const float2*)&h[(size_t)gi[n] * D + j0];
        float h0 = __shfl(h2.x, 0, 64);
        float h0c = fmaxf(h0, EPS1);
        float fac = facosh(h0c) * rsqrtf(h0c * h0c - 1.0f);
        ta[n] = (lane == 0) ? 0.0f : h2.x * fac;
        tb[n] = h2.y * fac;
        *(float2*)&ts[wv * 4 + n][j0] = make_float2(ta[n], tb[n]);
    }

    // ---- xt = t @ W ----
    float xta[4] = {0, 0, 0, 0}, xtb[4] = {0, 0, 0, 0};
    for (int k0 = 0; k0 < D; k0 += 4) {
        float4 tv0 = *(const float4*)&ts[wv * 4 + 0][k0];
        float4 tv1 = *(const float4*)&ts[wv * 4 + 1][k0];
        float4 tv2 = *(const float4*)&ts[wv * 4 + 2][k0];
        float4 tv3 = *(const float4*)&ts[wv * 4 + 3][k0];
        float2 w0 = *(const float2*)&W[(k0 + 0) * D + j0];
        float2 w1 = *(const float2*)&W[(k0 + 1) * D + j0];
        float2 w2 = *(const float2*)&W[(k0 + 2) * D + j0];
        float2 w3 = *(const float2*)&W[(k0 + 3) * D + j0];
        xta[0] = fmaf(tv0.x, w0.x, fmaf(tv0.y, w1.x, fmaf(tv0.z, w2.x, fmaf(tv0.w, w3.x, xta[0]))));
        xtb[0] = fmaf(tv0.x, w0.y, fmaf(tv0.y, w1.y, fmaf(tv0.z, w2.y, fmaf(tv0.w, w3.y, xtb[0]))));
        xta[1] = fmaf(tv1.x, w0.x, fmaf(tv1.y, w1.x, fmaf(tv1.z, w2.x, fmaf(tv1.w, w3.x, xta[1]))));
        xtb[1] = fmaf(tv1.x, w0.y, fmaf(tv1.y, w1.y, fmaf(tv1.z, w2.y, fmaf(tv1.w, w3.y, xtb[1]))));
        xta[2] = fmaf(tv2.x, w0.x, fmaf(tv2.y, w1.x, fmaf(tv2.z, w2.x, fmaf(tv2.w, w3.x, xta[2]))));
        xtb[2] = fmaf(tv2.x, w0.y, fmaf(tv2.y, w1.y, fmaf(tv2.z, w2.y, fmaf(tv2.w, w3.y, xtb[2]))));
        xta[3] = fmaf(tv3.x, w0.x, fmaf(tv3.y, w1.x, fmaf(tv3.z, w2.x, fmaf(tv3.w, w3.x, xta[3]))));
        xtb[3] = fmaf(tv3.x, w0.y, fmaf(tv3.y, w1.y, fmaf(tv3.z, w2.y, fmaf(tv3.w, w3.y, xtb[3]))));
    }
    if (lane == 0)
#pragma unroll
        for (int n = 0; n < 4; n++) xta[n] = 0.0f;

    // ---- x = expmap0([0,xt]); b = transp0(x,[0,bias]); xn = expmap(x,b) ----
    float2 bv = *(const float2*)&bias[j0];
    float va = (lane == 0) ? 0.0f : bv.x, vb = bv.y;
    float xna[4], xnb[4];
#pragma unroll
    for (int n = 0; n < 4; n++) {
        float nsq = wsum64(xta[n] * xta[n] + xtb[n] * xtb[n]);
        float nn = sqrtf(fmaxf(nsq, 1e-6f));
        float e = __expf(nn), ei = __fdividef(1.0f, e);
        float ch = 0.5f * (e + ei), sh = __fdividef(0.5f * (e - ei), nn);
        float xa = (lane == 0) ? ch : sh * xta[n];
        float xb = sh * xtb[n];
        float lxv = wsum64(xa * va + xb * vb);
        float coef = __fdividef(lxv, 1.0f + ch);
        float ba = (lane == 0) ? coef * (ch + 1.0f) : fmaf(coef, xa, va);
        float bb = fmaf(coef, xb, vb);
        float lbb = wsum64(((lane == 0) ? -ba * ba : ba * ba) + bb * bb);
        float nb = sqrtf(fmaxf(lbb, 1e-6f));
        float e2 = __expf(nb), ei2 = __fdividef(1.0f, e2);
        float ch2 = 0.5f * (e2 + ei2), sh2 = __fdividef(0.5f * (e2 - ei2), nb);
        xna[n] = ch2 * xa + sh2 * ba;
        xnb[n] = ch2 * xb + sh2 * bb;
        if (val[n])
            *(float2*)&XQ[(size_t)gi[n] * 256 + j0] = make_float2(xna[n], xnb[n]);
    }

    // ---- x_tan = logmap0(xn) -> LDS ----
#pragma unroll
    for (int n = 0; n < 4; n++) {
        float Y0 = __shfl(xna[n], 0, 64);
        float Y0c = fmaxf(Y0, EPS1);
        float f = facosh(Y0c) * rsqrtf(Y0c * Y0c - 1.0f);
        float xta2 = (lane == 0) ? 0.0f : xna[n] * f;
        float xtb2 = xnb[n] * f;
        *(float2*)&ts[wv * 4 + n][j0] = make_float2(xta2, xtb2);
    }

    // ---- P = x_tan @ W1a + b1 ; Q = x_tan @ W1b ----
    float pa[4] = {0, 0, 0, 0}, pb[4] = {0, 0, 0, 0};
    float qa[4] = {0, 0, 0, 0}, qb[4] = {0, 0, 0, 0};
    for (int k0 = 0; k0 < D; k0 += 4) {
        float4 tv0 = *(const float4*)&ts[wv * 4 + 0][k0];
        float4 tv1 = *(const float4*)&ts[wv * 4 + 1][k0];
        float4 tv2 = *(const float4*)&ts[wv * 4 + 2][k0];
        float4 tv3 = *(const float4*)&ts[wv * 4 + 3][k0];
        float2 a0 = *(const float2*)&att_w1[(k0 + 0) * D + j0];
        float2 a1 = *(const float2*)&att_w1[(k0 + 1) * D + j0];
        float2 a2 = *(const float2*)&att_w1[(k0 + 2) * D + j0];
        float2 a3 = *(const float2*)&att_w1[(k0 + 3) * D + j0];
        float2 c0 = *(const float2*)&att_w1[(D + k0 + 0) * D + j0];
        float2 c1 = *(const float2*)&att_w1[(D + k0 + 1) * D + j0];
        float2 c2 = *(const float2*)&att_w1[(D + k0 + 2) * D + j0];
        float2 c3 = *(const float2*)&att_w1[(D + k0 + 3) * D + j0];
        pa[0] = fmaf(tv0.x, a0.x, fmaf(tv0.y, a1.x, fmaf(tv0.z, a2.x, fmaf(tv0.w, a3.x, pa[0]))));
        pb[0] = fmaf(tv0.x, a0.y, fmaf(tv0.y, a1.y, fmaf(tv0.z, a2.y, fmaf(tv0.w, a3.y, pb[0]))));
        qa[0] = fmaf(tv0.x, c0.x, fmaf(tv0.y, c1.x, fmaf(tv0.z, c2.x, fmaf(tv0.w, c3.x, qa[0]))));
        qb[0] = fmaf(tv0.x, c0.y, fmaf(tv0.y, c1.y, fmaf(tv0.z, c2.y, fmaf(tv0.w, c3.y, qb[0]))));
        pa[1] = fmaf(tv1.x, a0.x, fmaf(tv1.y, a1.x, fmaf(tv1.z, a2.x, fmaf(tv1.w, a3.x, pa[1]))));
        pb[1] = fmaf(tv1.x, a0.y, fmaf(tv1.y, a1.y, fmaf(tv1.z, a2.y, fmaf(tv1.w, a3.y, pb[1]))));
        qa[1] = fmaf(tv1.x, c0.x, fmaf(tv1.y, c1.x, fmaf(tv1.z, c2.x, fmaf(tv1.w, c3.x, qa[1]))));
        qb[1] = fmaf(tv1.x, c0.y, fmaf(tv1.y, c1.y, fmaf(tv1.z, c2.y, fmaf(tv1.w, c3.y, qb[1]))));
        pa[2] = fmaf(tv2.x, a0.x, fmaf(tv2.y, a1.x, fmaf(tv2.z, a2.x, fmaf(tv2.w, a3.x, pa[2]))));
        pb[2] = fmaf(tv2.x, a0.y, fmaf(tv2.y, a1.y, fmaf(tv2.z, a2.y, fmaf(tv2.w, a3.y, pb[2]))));
        qa[2] = fmaf(tv2.x, c0.x, fmaf(tv2.y, c1.x, fmaf(tv2.z, c2.x, fmaf(tv2.w, c3.x, qa[2]))));
        qb[2] = fmaf(tv2.x, c0.y, fmaf(tv2.y, c1.y, fmaf(tv2.z, c2.y, fmaf(tv2.w, c3.y, qb[2]))));
        pa[3] = fmaf(tv3.x, a0.x, fmaf(tv3.y, a1.x, fmaf(tv3.z, a2.x, fmaf(tv3.w, a3.x, pa[3]))));
        pb[3] = fmaf(tv3.x, a0.y, fmaf(tv3.y, a1.y, fmaf(tv3.z, a2.y, fmaf(tv3.w, a3.y, pb[3]))));
        qa[3] = fmaf(tv3.x, c0.x, fmaf(tv3.y, c1.x, fmaf(tv3.z, c2.x, fmaf(tv3.w, c3.x, qa[3]))));
        qb[3] = fmaf(tv3.x, c0.y, fmaf(tv3.y, c1.y, fmaf(tv3.z, c2.y, fmaf(tv3.w, c3.y, qb[3]))));
    }
    float2 b1v = *(const float2*)&att_b1[j0];
#pragma unroll
    for (int n = 0; n < 4; n++) {
        if (val[n]) {
            *(float2*)&P_out[(size_t)gi[n] * D + j0] =
                make_float2(pa[n] + b1v.x, pb[n] + b1v.y);
            *(float2*)&XQ[(size_t)gi[n] * 256 + 128 + j0] =
                make_float2(qa[n], qb[n]);
        }
    }

    // ---- folded histogram ----
    int gtid = blockIdx.x * 256 + tid;
    int tot = gridDim.x * 256;
    for (int e2 = gtid; e2 < E; e2 += tot) atomicAdd(&cnt[row[e2]], 1);
}

// ---------------------------------------------------------------------------
// CSR build: one-pass scan (10 items/thread) + scatter
// ---------------------------------------------------------------------------
__global__ __launch_bounds__(1024) void scan_kernel(const int* __restrict__ cnt,
                                                    int* __restrict__ off,
                                                    int* __restrict__ cursor,
                                                    int N) {
    __shared__ int wt[16];
    int tid = threadIdx.x, lane = tid & 63, wid = tid >> 6;
    int PER = (N + 1023) >> 10;  // items per thread (<=16)
    int basei = tid * PER;
    int loc[16];
    int tsum = 0;
#pragma unroll 4
    for (int r = 0; r < PER; r++) {
        int idx = basei + r;
        int v = (idx < N) ? cnt[idx] : 0;
        loc[r] = tsum;  // exclusive within thread
        tsum += v;
    }
    int inc = tsum;
#pragma unroll
    for (int o = 1; o < 64; o <<= 1) {
        int t = __shfl_up(inc, o, 64);
        if (lane >= o) inc += t;
    }
    if (lane == 63) wt[wid] = inc;
    __syncthreads();
    if (tid < 16) {
        int w = wt[tid];
#pragma unroll
        for (int o = 1; o < 16; o <<= 1) {
            int t = __shfl_up(w, o, 64);
            if ((tid & 15) >= o) w += t;
        }
        wt[tid] = w;
    }
    __syncthreads();
    int wbase = (wid == 0) ? 0 : wt[wid - 1];
    int texcl = wbase + inc - tsum;
    for (int r = 0; r < PER; r++) {
        int idx = basei + r;
        if (idx < N) {
            int o = texcl + loc[r];
            off[idx] = o;
            cursor[idx] = o;
        }
    }
}

__global__ void scatter_kernel(const int* __restrict__ row,
                               const int* __restrict__ col,
                               const float* __restrict__ edge_attr,
                               const float* __restrict__ edge_mask,
                               int* __restrict__ cursor,
                               float4* __restrict__ rec, int E) {
    const float2* ea2 = (const float2*)edge_attr;
    for (int e = blockIdx.x * blockDim.x + threadIdx.x; e < E;
         e += gridDim.x * blockDim.x) {
        int r = row[e];
        int pos = atomicAdd(&cursor[r], 1);
        float2 a = ea2[e];
        rec[pos] = make_float4(__int_as_float(col[e]), a.x, a.y, edge_mask[e]);
    }
}

// ---------------------------------------------------------------------------
// Kernel D: STATIC edge aggregation + fused epilogue (R7 structure).
// One wave per node, 4 chunks (one per 16-lane group); DPP reductions;
// register-only epilogue; group 0 stores. No LDS, no barriers, no atomics.
// ---------------------------------------------------------------------------
__global__ __launch_bounds__(256) void edge_agg(
    const float* __restrict__ XQ, const float* __restrict__ P,
    const float4* __restrict__ rec, const int* __restrict__ off,
    const int* __restrict__ cnt, const float* __restrict__ w1c,
    const float* __restrict__ att_w2, const float* __restrict__ att_b2,
    const float* __restrict__ gamma, const float* __restrict__ beta,
    float* __restrict__ out, int N) {
    int tid = threadIdx.x, lane = tid & 63;
    int sub = lane & 15, grp = lane >> 4;
    int i = blockIdx.x * 4 + (tid >> 6);  // wave = node
    bool valid = i < N;
    i = min(i, N - 1);
    int j8 = sub * 8, f4 = sub * 2;

    const float4* w4 = (const float4*)w1c;
    const float4* aw4 = (const float4*)att_w2;
    const float4* xq4r = (const float4*)(XQ + (size_t)i * 256);
    const float4* pr4 = (const float4*)(P + (size_t)i * D);
    float xr[8], pr[8], wa[8], wb[8], wg[8], w2v[8];
    unpack8(xq4r[f4], xq4r[f4 + 1], xr);
    unpack8(pr4[f4], pr4[f4 + 1], pr);
    unpack8(w4[f4], w4[f4 + 1], wa);
    unpack8(w4[32 + f4], w4[32 + f4 + 1], wb);
    unpack8(w4[64 + f4], w4[64 + f4 + 1], wg);
    unpack8(aw4[f4], aw4[f4 + 1], w2v);
    float b2 = att_b2[0];
    float xr0s = (sub == 0) ? -xr[0] : xr[0];
    float g_ln[8], bt_ln[8];
#pragma unroll
    for (int u = 0; u < 8; u++) {
        int j = j8 + u;
        g_ln[u] = (j > 0) ? gamma[j - 1] : 0.0f;
        bt_ln[u] = (j > 0) ? beta[j - 1] : 0.0f;
    }

    float acc[8];
#pragma unroll
    for (int u = 0; u < 8; u++) acc[u] = 0.0f;

    int s = off[i], m = valid ? cnt[i] : 0;
    int clen = (m + 3) >> 2;           // wave-uniform chunk length
    int k0 = grp * clen;
    int len = min(m, k0 + clen) - k0;  // may be <=0 for trailing groups

    auto compute = [&](const float4& rc, const float4& g0, const float4& g1,
                       const float4& g2, const float4& g3, bool act) {
        float xc[8], qc[8];
        unpack8(g0, g1, xc);
        unpack8(g2, g3, qc);
        float lin = xr0s * xc[0];
#pragma unroll
        for (int u = 1; u < 8; u++) lin = fmaf(xr[u], xc[u], lin);
        lin = dpp_rsum16(lin);
        float alpha = fmaxf(-lin, EPS1);
        float a2m = fmaxf(fmaf(alpha, alpha, -1.0f), 1e-12f);
        float rden = rsqrtf(a2m);
        float geo = __logf(fmaf(a2m, rden, alpha));  // acosh(alpha)
        float lp = 0.0f;
#pragma unroll
        for (int u = 0; u < 8; u++) {
            float hv = pr[u] + qc[u] +
                       fmaf(rc.y, wa[u], fmaf(rc.z, wb[u], geo * wg[u]));
            float sig = __fdividef(1.0f, 1.0f + __expf(-hv));
            lp = fmaf(hv * sig, w2v[u], lp);  // silu(h)*w2
        }
        lp = dpp_rsum16(lp);
        float w = act ? rc.w : 0.0f;
        float att = w * __fdividef(1.0f, 1.0f + __expf(-(lp + b2)));
        float scale = att * geo * rden * 1e-3f;
#pragma unroll
        for (int u = 0; u < 8; u++)
            acc[u] = fmaf(scale, fmaf(-alpha, xr[u], xc[u]), acc[u]);
    };

    // software-pipelined chunk loop (depth 2), wave-uniform bound
    float4 rcA = make_float4(__int_as_float(0), 0.0f, 0.0f, 0.0f), rcB;
    if (len > 0) rcA = rec[s + k0];
    const float4* pA =
        (const float4*)(XQ + (size_t)__float_as_int(rcA.x) * 256);
    float4 gA0 = pA[f4], gA1 = pA[f4 + 1], gA2 = pA[32 + f4],
           gA3 = pA[32 + f4 + 1];
    float4 gB0, gB1, gB2, gB3;

    for (int t = 0; t < clen; t += 2) {
        rcB = rcA;
        if (t + 1 < len) rcB = rec[s + k0 + t + 1];
        const float4* pB =
            (const float4*)(XQ + (size_t)__float_as_int(rcB.x) * 256);
        gB0 = pB[f4]; gB1 = pB[f4 + 1]; gB2 = pB[32 + f4];
        gB3 = pB[32 + f4 + 1];
        compute(rcA, gA0, gA1, gA2, gA3, t < len);
        rcA = rcB;
        if (t + 2 < len) rcA = rec[s + k0 + t + 2];
        const float4* pN =
            (const float4*)(XQ + (size_t)__float_as_int(rcA.x) * 256);
        gA0 = pN[f4]; gA1 = pN[f4 + 1]; gA2 = pN[32 + f4];
        gA3 = pN[32 + f4 + 1];
        compute(rcB, gB0, gB1, gB2, gB3, t + 1 < len);
    }

    // merge the 4 chunk-partials: every lane gets the full sum
#pragma unroll
    for (int u = 0; u < 8; u++) {
        acc[u] += __shfl_xor(acc[u], 16, 64);
        acc[u] += __shfl_xor(acc[u], 32, 64);
    }

    // fused epilogue (all lanes compute; grp 0 stores)
    float lxa_p = (sub == 0) ? -xr[0] * acc[0] : xr[0] * acc[0];
#pragma unroll
    for (int u = 1; u < 8; u++) lxa_p = fmaf(xr[u], acc[u], lxa_p);
    float lxa = dpp_rsum16(lxa_p);
    float uj[8];
#pragma unroll
    for (int u = 0; u < 8; u++) uj[u] = fmaf(lxa, xr[u], acc[u]);
    float luu_p = (sub == 0) ? -uj[0] * uj[0] : uj[0] * uj[0];
#pragma unroll
    for (int u = 1; u < 8; u++) luu_p = fmaf(uj[u], uj[u], luu_p);
    float luu = dpp_rsum16(luu_p);
    float nn = sqrtf(fmaxf(luu, 1e-6f));
    float e = __expf(nn), ei = __fdividef(1.0f, e);
    float ch = 0.5f * (e + ei), shv = __fdividef(0.5f * (e - ei), nn);
    float xn[8];
#pragma unroll
    for (int u = 0; u < 8; u++) xn[u] = ch * xr[u] + shv * uj[u];
    float X0 = __shfl(xn[0], lane & 48, 64);  // group-base lane's j=0
    X0 = fmaxf(X0, EPS1);
    float fc = facosh(X0) * rsqrtf(X0 * X0 - 1.0f);
    float ht[8];
#pragma unroll
    for (int u = 0; u < 8; u++) ht[u] = xn[u] * fc;
    if (sub == 0) ht[0] = 0.0f;
    float mp = 0.0f;
#pragma unroll
    for (int u = 0; u < 8; u++) mp += ht[u];
    float mean = dpp_rsum16(mp) * (1.0f / 127.0f);
    float diff[8];
#pragma unroll
    for (int u = 0; u < 8; u++) diff[u] = ht[u] - mean;
    if (sub == 0) diff[0] = 0.0f;
    float vp = 0.0f;
#pragma unroll
    for (int u = 0; u < 8; u++) vp = fmaf(diff[u], diff[u], vp);
    float var = dpp_rsum16(vp) * (1.0f / 127.0f);
    float rstd = rsqrtf(var + 1e-5f);
    float sp[8];
#pragma unroll
    for (int u = 0; u < 8; u++)
        sp[u] = fmaf(diff[u] * rstd, g_ln[u], bt_ln[u]);
    if (sub == 0) sp[0] = 0.0f;
    float n2p = 0.0f;
#pragma unroll
    for (int u = 0; u < 8; u++) n2p = fmaf(sp[u], sp[u], n2p);
    float n2 = sqrtf(fmaxf(dpp_rsum16(n2p), 1e-6f));
    e = __expf(n2);
    ei = __fdividef(1.0f, e);
    float y0 = 0.5f * (e + ei), sh2 = __fdividef(0.5f * (e - ei), n2);
    float yj[8];
#pragma unroll
    for (int u = 0; u < 8; u++) yj[u] = sh2 * sp[u];
    if (sub == 0) yj[0] = y0;
    float y0c = fmaxf(y0, EPS1);
    float f3 = facosh(y0c) * rsqrtf(y0c * y0c - 1.0f);
    float sj[8];
#pragma unroll
    for (int u = 0; u < 8; u++) {
        float lj = yj[u] * f3;
        sj[u] = __fdividef(lj, 1.0f + __expf(-lj));
    }
    if (sub == 0) sj[0] = 0.0f;
    float n3p = 0.0f;
#pragma unroll
    for (int u = 0; u < 8; u++) n3p = fmaf(sj[u], sj[u], n3p);
    float n3 = sqrtf(fmaxf(dpp_rsum16(n3p), 1e-6f));
    e = __expf(n3);
    ei = __fdividef(1.0f, e);
    float o0 = 0.5f * (e + ei), sh3 = __fdividef(0.5f * (e - ei), n3);
    float ov[8];
#pragma unroll
    for (int u = 0; u < 8; u++) ov[u] = sh3 * sj[u];
    if (sub == 0) ov[0] = o0;
    if (valid && grp == 0) {
        float4* o4 = (float4*)(out + (size_t)i * D);
        o4[f4] = make_float4(ov[0], ov[1], ov[2], ov[3]);
        o4[f4 + 1] = make_float4(ov[4], ov[5], ov[6], ov[7]);
    }
}

extern "C" void kernel_launch(void* const* d_in, const int* in_sizes, int n_in,
                              void* d_out, int out_size, void* d_ws,
                              size_t ws_size, hipStream_t stream) {
    const float* h = (const float*)d_in[0];
    const float* edge_attr = (const float*)d_in[1];
    const int* row = (const int*)d_in[2];
    const int* col = (const int*)d_in[3];
    const float* edge_mask = (const float*)d_in[5];
    const float* W = (const float*)d_in[6];
    const float* bias = (const float*)d_in[7];
    const float* att_w1 = (const float*)d_in[8];
    const float* att_b1 = (const float*)d_in[9];
    const float* att_w2 = (const float*)d_in[10];
    const float* att_b2 = (const float*)d_in[11];
    const float* ln_g = (const float*)d_in[12];
    const float* ln_b = (const float*)d_in[13];

    int N = in_sizes[0] / D;
    int E = in_sizes[2];

    float* XQ = (float*)d_ws;                       // N*256
    float* Pbuf = XQ + (size_t)N * 256;             // N*128
    float4* rec = (float4*)(Pbuf + (size_t)N * D);  // E
    int* cnt = (int*)(rec + E);
    int* off = cnt + N;
    int* cur = off + N;

    hipMemsetAsync(cnt, 0, N * sizeof(int), stream);
    node_pre16<<<(N + 15) / 16, 256, 0, stream>>>(
        h, W, bias, att_w1, att_b1, XQ, Pbuf, row, cnt, N, E);
    scan_kernel<<<1, 1024, 0, stream>>>(cnt, off, cur, N);
    scatter_kernel<<<640, 256, 0, stream>>>(row, col, edge_attr, edge_mask,
                                            cur, rec, E);
    edge_agg<<<(N + 3) / 4, 256, 0, stream>>>(XQ, Pbuf, rec, off, cnt,
                                              att_w1 + 256 * D, att_w2, att_b2,
                                              ln_g, ln_b, (float*)d_out, N);
}

// Round 10
// 145.118 us; speedup vs baseline: 2.1571x; 1.0628x over previous
//
#include <hip/hip_runtime.h>
#include <hip/hip_fp16.h>
#include <math.h>

#define D 128
#define NPB 8
#define EPS1 (1.0f + 1e-6f)

// ---- DPP row_ror sum over each 16-lane row: all lanes get the total ----
__device__ __forceinline__ float dpp_rsum16(float v) {
    v += __int_as_float(__builtin_amdgcn_update_dpp(
        0, __float_as_int(v), 0x121, 0xf, 0xf, true));  // ror:1
    v += __int_as_float(__builtin_amdgcn_update_dpp(
        0, __float_as_int(v), 0x122, 0xf, 0xf, true));  // ror:2
    v += __int_as_float(__builtin_amdgcn_update_dpp(
        0, __float_as_int(v), 0x124, 0xf, 0xf, true));  // ror:4
    v += __int_as_float(__builtin_amdgcn_update_dpp(
        0, __float_as_int(v), 0x128, 0xf, 0xf, true));  // ror:8
    return v;
}

// fast acosh for a >= 1+1e-6
__device__ __forceinline__ float facosh(float a) {
    return __logf(a + sqrtf(fmaxf(a * a - 1.0f, 0.0f)));
}

__device__ __forceinline__ void unpack8(const float4& a, const float4& b,
                                        float* d) {
    d[0] = a.x; d[1] = a.y; d[2] = a.z; d[3] = a.w;
    d[4] = b.x; d[5] = b.y; d[6] = b.z; d[7] = b.w;
}

// 8 halfs packed in a float4 -> 8 floats
__device__ __forceinline__ void unpackh8(const float4& v, float* d) {
    const __half2* p = (const __half2*)&v;
#pragma unroll
    for (int t = 0; t < 4; t++) {
        float2 f = __half22float2(p[t]);
        d[2 * t] = f.x;
        d[2 * t + 1] = f.y;
    }
}

// ---------------------------------------------------------------------------
// Kernel 1: per-node pre-processing (R7 512-thread k-split structure).
// 512 threads = (j in [0,128)) x (kp in {0..3}). Elementwise: quarter kp owns
// nodes [kp*2, kp*2+2). Matmuls: thread (j,kp) computes partials over
// k in [kp*32,(kp+1)*32) for ALL 8 nodes; merge via LDS psum.
// Outputs: Xrow fp32 (row side), XQh fp16 (gather side: x|Q), P fp32.
// Tail: grid-stride histogram.
// ---------------------------------------------------------------------------
__device__ __forceinline__ void bsumH2(float* v, float (*wred)[2], int lane,
                                       int wid, int kp) {
    __syncthreads();  // protect wred reuse
#pragma unroll
    for (int o = 32; o; o >>= 1)
#pragma unroll
        for (int nl = 0; nl < 2; nl++) v[nl] += __shfl_xor(v[nl], o, 64);
    if (lane == 0)
#pragma unroll
        for (int nl = 0; nl < 2; nl++) wred[wid][nl] = v[nl];
    __syncthreads();
#pragma unroll
    for (int nl = 0; nl < 2; nl++)
        v[nl] = wred[2 * kp][nl] + wred[2 * kp + 1][nl];
}

__global__ __launch_bounds__(512) void node_pre8(
    const float* __restrict__ h, const float* __restrict__ W,
    const float* __restrict__ bias, const float* __restrict__ att_w1,
    const float* __restrict__ att_b1, float* __restrict__ Xrow,
    __half* __restrict__ XQh, float* __restrict__ P_out,
    const int* __restrict__ row, int* __restrict__ cnt, int N, int E) {
    int i0 = blockIdx.x * NPB;
    int tid = threadIdx.x;
    int j = tid & 127, kp = tid >> 7;
    int lane = tid & 63, wid = tid >> 6;
    int nbase = kp * 2;
    __shared__ __align__(16) float t8[NPB][D];
    __shared__ float psumP[4][NPB][D];
    __shared__ float psumQ[4][NPB][D];
    __shared__ float wred[8][2];

    // logmap0(h) — own 2 nodes
    float hj[2];
#pragma unroll
    for (int nl = 0; nl < 2; nl++) {
        int gi = i0 + nbase + nl;
        hj[nl] = (gi < N) ? h[(size_t)gi * D + j] : 0.0f;
        t8[nbase + nl][j] = hj[nl];
    }
    __syncthreads();
    float tj[2];
#pragma unroll
    for (int nl = 0; nl < 2; nl++) {
        float h0 = fmaxf(t8[nbase + nl][0], EPS1);
        float fac = facosh(h0) * rsqrtf(h0 * h0 - 1.0f);
        tj[nl] = (j == 0) ? 0.0f : hj[nl] * fac;
    }
    __syncthreads();
#pragma unroll
    for (int nl = 0; nl < 2; nl++) t8[nbase + nl][j] = tj[nl];
    __syncthreads();

    // xt partial over this thread's k-quarter, all 8 nodes
    float xtp[NPB];
#pragma unroll
    for (int n = 0; n < NPB; n++) xtp[n] = 0.0f;
    int kbeg = kp * 32;
    for (int k0 = kbeg; k0 < kbeg + 32; k0 += 4) {
        float w0 = W[(k0 + 0) * D + j], w1 = W[(k0 + 1) * D + j];
        float w2 = W[(k0 + 2) * D + j], w3 = W[(k0 + 3) * D + j];
#pragma unroll
        for (int n = 0; n < NPB; n++) {
            float4 tv = *(const float4*)&t8[n][k0];
            xtp[n] = fmaf(tv.x, w0,
                          fmaf(tv.y, w1, fmaf(tv.z, w2, fmaf(tv.w, w3, xtp[n]))));
        }
    }
#pragma unroll
    for (int n = 0; n < NPB; n++) psumP[kp][n][j] = xtp[n];
    __syncthreads();
    float xt[2];
#pragma unroll
    for (int nl = 0; nl < 2; nl++) {
        int n = nbase + nl;
        xt[nl] = (j == 0) ? 0.0f
                          : (psumP[0][n][j] + psumP[1][n][j] + psumP[2][n][j] +
                             psumP[3][n][j]);
    }

    // x = expmap0([0, xt])
    float v2[2];
#pragma unroll
    for (int nl = 0; nl < 2; nl++) v2[nl] = xt[nl] * xt[nl];
    bsumH2(v2, wred, lane, wid, kp);
    float xj[2];
#pragma unroll
    for (int nl = 0; nl < 2; nl++) {
        float nn = sqrtf(fmaxf(v2[nl], 1e-6f));
        float e = __expf(nn), ei = __fdividef(1.0f, e);
        float ch = 0.5f * (e + ei), sh = 0.5f * (e - ei);
        xj[nl] = (j == 0) ? ch : __fdividef(sh, nn) * xt[nl];
    }

    // b = transp0(x, [0,bias]); x = expmap(x, b)
    float vj = (j == 0) ? 0.0f : bias[j];
#pragma unroll
    for (int nl = 0; nl < 2; nl++) v2[nl] = xj[nl] * vj;
    bsumH2(v2, wred, lane, wid, kp);
    __syncthreads();
#pragma unroll
    for (int nl = 0; nl < 2; nl++) t8[nbase + nl][j] = xj[nl];
    __syncthreads();
    float bj[2];
#pragma unroll
    for (int nl = 0; nl < 2; nl++) {
        float X0 = t8[nbase + nl][0];
        float coef = __fdividef(v2[nl], 1.0f + X0);
        bj[nl] = vj + coef * ((j == 0) ? (X0 + 1.0f) : xj[nl]);
    }
#pragma unroll
    for (int nl = 0; nl < 2; nl++)
        v2[nl] = (j == 0) ? -bj[nl] * bj[nl] : bj[nl] * bj[nl];
    bsumH2(v2, wred, lane, wid, kp);
    float xnj[2];
#pragma unroll
    for (int nl = 0; nl < 2; nl++) {
        float nb = sqrtf(fmaxf(v2[nl], 1e-6f));
        float e = __expf(nb), ei = __fdividef(1.0f, e);
        float ch = 0.5f * (e + ei), sh = 0.5f * (e - ei);
        xnj[nl] = ch * xj[nl] + __fdividef(sh, nb) * bj[nl];
        int gi = i0 + nbase + nl;
        if (gi < N) {
            Xrow[(size_t)gi * D + j] = xnj[nl];
            XQh[(size_t)gi * 256 + j] = __float2half(xnj[nl]);
        }
    }

    // x_tan = logmap0(x) -> t8
    __syncthreads();
#pragma unroll
    for (int nl = 0; nl < 2; nl++) t8[nbase + nl][j] = xnj[nl];
    __syncthreads();
    float xtj[2];
#pragma unroll
    for (int nl = 0; nl < 2; nl++) {
        float Y0 = fmaxf(t8[nbase + nl][0], EPS1);
        float f = facosh(Y0) * rsqrtf(Y0 * Y0 - 1.0f);
        xtj[nl] = (j == 0) ? 0.0f : xnj[nl] * f;
    }
    __syncthreads();
#pragma unroll
    for (int nl = 0; nl < 2; nl++) t8[nbase + nl][j] = xtj[nl];
    __syncthreads();

    // P/Q partials over k-quarter, all 8 nodes
    float pp[NPB], qq[NPB];
#pragma unroll
    for (int n = 0; n < NPB; n++) {
        pp[n] = 0.0f;
        qq[n] = 0.0f;
    }
    for (int k0 = kbeg; k0 < kbeg + 32; k0 += 4) {
        float a0 = att_w1[(k0 + 0) * D + j], a1 = att_w1[(k0 + 1) * D + j];
        float a2 = att_w1[(k0 + 2) * D + j], a3 = att_w1[(k0 + 3) * D + j];
        float c0 = att_w1[(D + k0 + 0) * D + j], c1 = att_w1[(D + k0 + 1) * D + j];
        float c2 = att_w1[(D + k0 + 2) * D + j], c3 = att_w1[(D + k0 + 3) * D + j];
#pragma unroll
        for (int n = 0; n < NPB; n++) {
            float4 tv = *(const float4*)&t8[n][k0];
            pp[n] = fmaf(tv.x, a0,
                         fmaf(tv.y, a1, fmaf(tv.z, a2, fmaf(tv.w, a3, pp[n]))));
            qq[n] = fmaf(tv.x, c0,
                         fmaf(tv.y, c1, fmaf(tv.z, c2, fmaf(tv.w, c3, qq[n]))));
        }
    }
#pragma unroll
    for (int n = 0; n < NPB; n++) {
        psumP[kp][n][j] = pp[n];
        psumQ[kp][n][j] = qq[n];
    }
    __syncthreads();
    float b1 = att_b1[j];
#pragma unroll
    for (int nl = 0; nl < 2; nl++) {
        int n = nbase + nl;
        int gi = i0 + n;
        if (gi < N) {
            P_out[(size_t)gi * D + j] = psumP[0][n][j] + psumP[1][n][j] +
                                        psumP[2][n][j] + psumP[3][n][j] + b1;
            float q = psumQ[0][n][j] + psumQ[1][n][j] + psumQ[2][n][j] +
                      psumQ[3][n][j];
            XQh[(size_t)gi * 256 + 128 + j] = __float2half(q);
        }
    }

    // ---- folded histogram ----
    int gtid = blockIdx.x * 512 + tid;
    int tot = gridDim.x * 512;
    for (int e2 = gtid; e2 < E; e2 += tot) atomicAdd(&cnt[row[e2]], 1);
}

// ---------------------------------------------------------------------------
// CSR build: one-pass scan + scatter
// ---------------------------------------------------------------------------
__global__ __launch_bounds__(1024) void scan_kernel(const int* __restrict__ cnt,
                                                    int* __restrict__ off,
                                                    int* __restrict__ cursor,
                                                    int N) {
    __shared__ int wt[16];
    int tid = threadIdx.x, lane = tid & 63, wid = tid >> 6;
    int PER = (N + 1023) >> 10;  // items per thread (<=16)
    int basei = tid * PER;
    int loc[16];
    int tsum = 0;
#pragma unroll 4
    for (int r = 0; r < PER; r++) {
        int idx = basei + r;
        int v = (idx < N) ? cnt[idx] : 0;
        loc[r] = tsum;  // exclusive within thread
        tsum += v;
    }
    int inc = tsum;
#pragma unroll
    for (int o = 1; o < 64; o <<= 1) {
        int t = __shfl_up(inc, o, 64);
        if (lane >= o) inc += t;
    }
    if (lane == 63) wt[wid] = inc;
    __syncthreads();
    if (tid < 16) {
        int w = wt[tid];
#pragma unroll
        for (int o = 1; o < 16; o <<= 1) {
            int t = __shfl_up(w, o, 64);
            if ((tid & 15) >= o) w += t;
        }
        wt[tid] = w;
    }
    __syncthreads();
    int wbase = (wid == 0) ? 0 : wt[wid - 1];
    int texcl = wbase + inc - tsum;
    for (int r = 0; r < PER; r++) {
        int idx = basei + r;
        if (idx < N) {
            int o = texcl + loc[r];
            off[idx] = o;
            cursor[idx] = o;
        }
    }
}

__global__ void scatter_kernel(const int* __restrict__ row,
                               const int* __restrict__ col,
                               const float* __restrict__ edge_attr,
                               const float* __restrict__ edge_mask,
                               int* __restrict__ cursor,
                               float4* __restrict__ rec, int E) {
    const float2* ea2 = (const float2*)edge_attr;
    for (int e = blockIdx.x * blockDim.x + threadIdx.x; e < E;
         e += gridDim.x * blockDim.x) {
        int r = row[e];
        int pos = atomicAdd(&cursor[r], 1);
        float2 a = ea2[e];
        rec[pos] = make_float4(__int_as_float(col[e]), a.x, a.y, edge_mask[e]);
    }
}

// ---------------------------------------------------------------------------
// Kernel D: edge aggregation (fp16 gathers) + fused fp32 epilogue.
// One wave per node, 4 chunks (one per 16-lane group); DPP reductions;
// register-only epilogue; group 0 stores. No LDS, no barriers, no atomics.
// ---------------------------------------------------------------------------
__global__ __launch_bounds__(256) void edge_agg(
    const float* __restrict__ Xrow, const float* __restrict__ P,
    const __half* __restrict__ XQh, const float4* __restrict__ rec,
    const int* __restrict__ off, const int* __restrict__ cnt,
    const float* __restrict__ w1c, const float* __restrict__ att_w2,
    const float* __restrict__ att_b2, const float* __restrict__ gamma,
    const float* __restrict__ beta, float* __restrict__ out, int N) {
    int tid = threadIdx.x, lane = tid & 63;
    int sub = lane & 15, grp = lane >> 4;
    int i = blockIdx.x * 4 + (tid >> 6);  // wave = node
    bool valid = i < N;
    i = min(i, N - 1);
    int j8 = sub * 8, f4 = sub * 2;

    const float4* w4 = (const float4*)w1c;
    const float4* aw4 = (const float4*)att_w2;
    const float4* xr4 = (const float4*)(Xrow + (size_t)i * D);
    const float4* pr4 = (const float4*)(P + (size_t)i * D);
    float xr[8], pr[8], wa[8], wb[8], wg[8], w2v[8];
    unpack8(xr4[f4], xr4[f4 + 1], xr);
    unpack8(pr4[f4], pr4[f4 + 1], pr);
    unpack8(w4[f4], w4[f4 + 1], wa);
    unpack8(w4[32 + f4], w4[32 + f4 + 1], wb);
    unpack8(w4[64 + f4], w4[64 + f4 + 1], wg);
    unpack8(aw4[f4], aw4[f4 + 1], w2v);
    float b2 = att_b2[0];
    float xr0s = (sub == 0) ? -xr[0] : xr[0];

    float acc[8];
#pragma unroll
    for (int u = 0; u < 8; u++) acc[u] = 0.0f;

    int s = off[i], m = valid ? cnt[i] : 0;
    int clen = (m + 3) >> 2;           // wave-uniform chunk length
    int k0 = grp * clen;
    int len = min(m, k0 + clen) - k0;  // may be <=0 for trailing groups

    auto compute = [&](const float4& rc, const float4& g0, const float4& g1,
                       bool act) {
        float xc[8], qc[8];
        unpackh8(g0, xc);
        unpackh8(g1, qc);
        float lin = xr0s * xc[0];
#pragma unroll
        for (int u = 1; u < 8; u++) lin = fmaf(xr[u], xc[u], lin);
        lin = dpp_rsum16(lin);
        float alpha = fmaxf(-lin, EPS1);
        float a2m = fmaxf(fmaf(alpha, alpha, -1.0f), 1e-12f);
        float rden = rsqrtf(a2m);
        float geo = __logf(fmaf(a2m, rden, alpha));  // acosh(alpha)
        float lp = 0.0f;
#pragma unroll
        for (int u = 0; u < 8; u++) {
            float hv = pr[u] + qc[u] +
                       fmaf(rc.y, wa[u], fmaf(rc.z, wb[u], geo * wg[u]));
            float sig = __fdividef(1.0f, 1.0f + __expf(-hv));
            lp = fmaf(hv * sig, w2v[u], lp);  // silu(h)*w2
        }
        lp = dpp_rsum16(lp);
        float w = act ? rc.w : 0.0f;
        float att = w * __fdividef(1.0f, 1.0f + __expf(-(lp + b2)));
        float scale = att * geo * rden * 1e-3f;
#pragma unroll
        for (int u = 0; u < 8; u++)
            acc[u] = fmaf(scale, fmaf(-alpha, xr[u], xc[u]), acc[u]);
    };

    // software-pipelined chunk loop (depth 2), wave-uniform bound
    float4 rcA = make_float4(__int_as_float(0), 0.0f, 0.0f, 0.0f), rcB;
    if (len > 0) rcA = rec[s + k0];
    const float4* pA =
        (const float4*)(XQh + (size_t)__float_as_int(rcA.x) * 256);
    float4 gA0 = pA[sub], gA1 = pA[16 + sub];
    float4 gB0, gB1;

    for (int t = 0; t < clen; t += 2) {
        rcB = rcA;
        if (t + 1 < len) rcB = rec[s + k0 + t + 1];
        const float4* pB =
            (const float4*)(XQh + (size_t)__float_as_int(rcB.x) * 256);
        gB0 = pB[sub];
        gB1 = pB[16 + sub];
        compute(rcA, gA0, gA1, t < len);
        rcA = rcB;
        if (t + 2 < len) rcA = rec[s + k0 + t + 2];
        const float4* pN =
            (const float4*)(XQh + (size_t)__float_as_int(rcA.x) * 256);
        gA0 = pN[sub];
        gA1 = pN[16 + sub];
        compute(rcB, gB0, gB1, t + 1 < len);
    }

    // merge the 4 chunk-partials: every lane gets the full sum
#pragma unroll
    for (int u = 0; u < 8; u++) {
        acc[u] += __shfl_xor(acc[u], 16, 64);
        acc[u] += __shfl_xor(acc[u], 32, 64);
    }

    // fused epilogue (all lanes compute; grp 0 stores)
    float lxa_p = (sub == 0) ? -xr[0] * acc[0] : xr[0] * acc[0];
#pragma unroll
    for (int u = 1; u < 8; u++) lxa_p = fmaf(xr[u], acc[u], lxa_p);
    float lxa = dpp_rsum16(lxa_p);
    float uj[8];
#pragma unroll
    for (int u = 0; u < 8; u++) uj[u] = fmaf(lxa, xr[u], acc[u]);
    float luu_p = (sub == 0) ? -uj[0] * uj[0] : uj[0] * uj[0];
#pragma unroll
    for (int u = 1; u < 8; u++) luu_p = fmaf(uj[u], uj[u], luu_p);
    float luu = dpp_rsum16(luu_p);
    float nn = sqrtf(fmaxf(luu, 1e-6f));
    float e = __expf(nn), ei = __fdividef(1.0f, e);
    float ch = 0.5f * (e + ei), shv = __fdividef(0.5f * (e - ei), nn);
    float xn[8];
#pragma unroll
    for (int u = 0; u < 8; u++) xn[u] = ch * xr[u] + shv * uj[u];
    float X0 = __shfl(xn[0], lane & 48, 64);  // group-base lane's j=0
    X0 = fmaxf(X0, EPS1);
    float fc = facosh(X0) * rsqrtf(X0 * X0 - 1.0f);
    float ht[8];
#pragma unroll
    for (int u = 0; u < 8; u++) ht[u] = xn[u] * fc;
    if (sub == 0) ht[0] = 0.0f;
    float mp = 0.0f;
#pragma unroll
    for (int u = 0; u < 8; u++) mp += ht[u];
    float mean = dpp_rsum16(mp) * (1.0f / 127.0f);
    float diff[8];
#pragma unroll
    for (int u = 0; u < 8; u++) diff[u] = ht[u] - mean;
    if (sub == 0) diff[0] = 0.0f;
    float vp = 0.0f;
#pragma unroll
    for (int u = 0; u < 8; u++) vp = fmaf(diff[u], diff[u], vp);
    float var = dpp_rsum16(vp) * (1.0f / 127.0f);
    float rstd = rsqrtf(var + 1e-5f);
    float sp[8];
#pragma unroll
    for (int u = 0; u < 8; u++) {
        int j = j8 + u;
        float g = (j > 0) ? gamma[j - 1] : 0.0f;
        float bt = (j > 0) ? beta[j - 1] : 0.0f;
        sp[u] = fmaf(diff[u] * rstd, g, bt);
    }
    if (sub == 0) sp[0] = 0.0f;
    float n2p = 0.0f;
#pragma unroll
    for (int u = 0; u < 8; u++) n2p = fmaf(sp[u], sp[u], n2p);
    float n2 = sqrtf(fmaxf(dpp_rsum16(n2p), 1e-6f));
    e = __expf(n2);
    ei = __fdividef(1.0f, e);
    float y0 = 0.5f * (e + ei), sh2 = __fdividef(0.5f * (e - ei), n2);
    float yj[8];
#pragma unroll
    for (int u = 0; u < 8; u++) yj[u] = sh2 * sp[u];
    if (sub == 0) yj[0] = y0;
    float y0c = fmaxf(y0, EPS1);
    float f3 = facosh(y0c) * rsqrtf(y0c * y0c - 1.0f);
    float sj[8];
#pragma unroll
    for (int u = 0; u < 8; u++) {
        float lj = yj[u] * f3;
        sj[u] = __fdividef(lj, 1.0f + __expf(-lj));
    }
    if (sub == 0) sj[0] = 0.0f;
    float n3p = 0.0f;
#pragma unroll
    for (int u = 0; u < 8; u++) n3p = fmaf(sj[u], sj[u], n3p);
    float n3 = sqrtf(fmaxf(dpp_rsum16(n3p), 1e-6f));
    e = __expf(n3);
    ei = __fdividef(1.0f, e);
    float o0 = 0.5f * (e + ei), sh3 = __fdividef(0.5f * (e - ei), n3);
    float ov[8];
#pragma unroll
    for (int u = 0; u < 8; u++) ov[u] = sh3 * sj[u];
    if (sub == 0) ov[0] = o0;
    if (valid && grp == 0) {
        float4* o4 = (float4*)(out + (size_t)i * D);
        o4[f4] = make_float4(ov[0], ov[1], ov[2], ov[3]);
        o4[f4 + 1] = make_float4(ov[4], ov[5], ov[6], ov[7]);
    }
}

extern "C" void kernel_launch(void* const* d_in, const int* in_sizes, int n_in,
                              void* d_out, int out_size, void* d_ws,
                              size_t ws_size, hipStream_t stream) {
    const float* h = (const float*)d_in[0];
    const float* edge_attr = (const float*)d_in[1];
    const int* row = (const int*)d_in[2];
    const int* col = (const int*)d_in[3];
    const float* edge_mask = (const float*)d_in[5];
    const float* W = (const float*)d_in[6];
    const float* bias = (const float*)d_in[7];
    const float* att_w1 = (const float*)d_in[8];
    const float* att_b1 = (const float*)d_in[9];
    const float* att_w2 = (const float*)d_in[10];
    const float* att_b2 = (const float*)d_in[11];
    const float* ln_g = (const float*)d_in[12];
    const float* ln_b = (const float*)d_in[13];

    int N = in_sizes[0] / D;
    int E = in_sizes[2];

    float* Xrow = (float*)d_ws;                      // N*128 fp32
    float* Pbuf = Xrow + (size_t)N * D;              // N*128 fp32
    __half* XQh = (__half*)(Pbuf + (size_t)N * D);   // N*256 fp16
    float4* rec = (float4*)(XQh + (size_t)N * 256);  // E recs
    int* cnt = (int*)(rec + E);
    int* off = cnt + N;
    int* cur = off + N;

    hipMemsetAsync(cnt, 0, N * sizeof(int), stream);
    node_pre8<<<(N + NPB - 1) / NPB, 512, 0, stream>>>(
        h, W, bias, att_w1, att_b1, Xrow, XQh, Pbuf, row, cnt, N, E);
    scan_kernel<<<1, 1024, 0, stream>>>(cnt, off, cur, N);
    scatter_kernel<<<640, 256, 0, stream>>>(row, col, edge_attr, edge_mask,
                                            cur, rec, E);
    edge_agg<<<(N + 3) / 4, 256, 0, stream>>>(Xrow, Pbuf, XQh, rec, off, cnt,
                                              att_w1 + 256 * D, att_w2, att_b2,
                                              ln_g, ln_b, (float*)d_out, N);
}